// Round 1
// baseline (318.494 us; speedup 1.0000x reference)
//
#include <hip/hip_runtime.h>
#include <hip/hip_bf16.h>
#include <stdint.h>

// Sizes (fixed by the problem)
// B=4096, A=768, V=2048, H=512, F=1024, ND=16, NC=2, NE=8, NL=3

typedef __attribute__((ext_vector_type(8))) short bf16x8;
typedef __attribute__((ext_vector_type(4))) float f32x4;

__device__ inline short f2b(float f) {
  union { float f; uint32_t u; } a; a.f = f;
  uint32_t r = a.u + 0x7fffu + ((a.u >> 16) & 1u);   // RNE
  return (short)(r >> 16);
}
__device__ inline float b2f(short s) {
  union { uint32_t u; float f; } a; a.u = ((uint32_t)(uint16_t)s) << 16;
  return a.f;
}
__device__ inline void gload_lds16(const void* g, void* l) {
  __builtin_amdgcn_global_load_lds(
      (const __attribute__((address_space(1))) uint32_t*)g,
      (__attribute__((address_space(3))) uint32_t*)l, 16, 0, 0);
}

// ---------------- conversions ----------------
__global__ __launch_bounds__(256)
void conv_k(const float* __restrict__ in, short* __restrict__ out, int n) {
  int i = (blockIdx.x * 256 + threadIdx.x) << 2;
  if (i >= n) return;
  float4 v = *(const float4*)(in + i);
  short4 o; o.x = f2b(v.x); o.y = f2b(v.y); o.z = f2b(v.z); o.w = f2b(v.w);
  *(short4*)(out + i) = o;
}

// out[n*ldout + k] = bf16(in[k*N + n]); grid (N/32, K/32, batch)
__global__ __launch_bounds__(256)
void convT_k(const float* __restrict__ in, short* __restrict__ out,
             int N, int ldout, long instride, long outstride) {
  in  += (long)blockIdx.z * instride;
  out += (long)blockIdx.z * outstride;
  __shared__ float t[32][33];
  const int tx = threadIdx.x & 31, ty = threadIdx.x >> 5;  // 32 x 8
  const int n0 = blockIdx.x << 5, k0 = blockIdx.y << 5;
#pragma unroll
  for (int i = 0; i < 4; ++i)
    t[ty + 8 * i][tx] = in[(long)(k0 + ty + 8 * i) * N + n0 + tx];
  __syncthreads();
#pragma unroll
  for (int i = 0; i < 4; ++i)
    out[(long)(n0 + ty + 8 * i) * ldout + k0 + tx] = f2b(t[tx][ty + 8 * i]);
}

// ---------------- main GEMM: C = A(MxK, bf16) * BT(NxK, bf16)^T ----------------
// 128x128 tile, BK=64, 4 waves (2x2), 16x16x32 MFMA. M,N multiples of 128, K of 64.
template<bool RELU, bool HASF32>
__global__ __launch_bounds__(256, 2)
void gemm_bt(const short* __restrict__ A, const short* __restrict__ BT,
             const float* __restrict__ bias,
             short* __restrict__ Cb, int ldcb,
             float* __restrict__ Cf, int ldcf,
             int K, int lda, int ldbt) {
  __shared__ short lsA[128 * 64];
  __shared__ short lsB[128 * 64];
  const int tid = threadIdx.x;
  const int w = tid >> 6, l = tid & 63;
  const int m0 = blockIdx.x << 7;
  const int n0 = blockIdx.y << 7;
  const int wr = w >> 1, wc = w & 1;
  const int lr = l & 15, lk = (l >> 4) << 3;

  f32x4 acc[4][4];
#pragma unroll
  for (int m = 0; m < 4; ++m)
#pragma unroll
    for (int n = 0; n < 4; ++n) acc[m][n] = (f32x4)0.f;

  const int r_ = tid >> 3;            // 0..31
  const int kc_ = (tid & 7) << 3;     // 0..56
  const short* Arow = A + (long)(m0 + r_) * lda + kc_;
  const short* Brow = BT + (long)(n0 + r_) * ldbt + kc_;

  for (int kt = 0; kt < K; kt += 64) {
#pragma unroll
    for (int i = 0; i < 4; ++i) {
      gload_lds16(Arow + (long)i * 32 * lda + kt, (char*)lsA + (i * 256 + w * 64) * 16);
      gload_lds16(Brow + (long)i * 32 * ldbt + kt, (char*)lsB + (i * 256 + w * 64) * 16);
    }
    __syncthreads();
#pragma unroll
    for (int kk = 0; kk < 64; kk += 32) {
      bf16x8 a[4], b[4];
#pragma unroll
      for (int m = 0; m < 4; ++m)
        a[m] = *(const bf16x8*)&lsA[(wr * 64 + m * 16 + lr) * 64 + kk + lk];
#pragma unroll
      for (int n = 0; n < 4; ++n)
        b[n] = *(const bf16x8*)&lsB[(wc * 64 + n * 16 + lr) * 64 + kk + lk];
#pragma unroll
      for (int m = 0; m < 4; ++m)
#pragma unroll
        for (int n = 0; n < 4; ++n)
          acc[m][n] = __builtin_amdgcn_mfma_f32_16x16x32_bf16(a[m], b[n], acc[m][n], 0, 0, 0);
    }
    __syncthreads();
  }

  const int lrow = (l >> 4) << 2;
#pragma unroll
  for (int n = 0; n < 4; ++n) {
    const int col = n0 + wc * 64 + n * 16 + lr;
    const float bz = bias ? bias[col] : 0.f;
#pragma unroll
    for (int m = 0; m < 4; ++m) {
      const int rowb = m0 + wr * 64 + m * 16 + lrow;
#pragma unroll
      for (int i = 0; i < 4; ++i) {
        float v = acc[m][n][i] + bz;
        if (RELU) v = fmaxf(v, 0.f);
        Cb[(long)(rowb + i) * ldcb + col] = f2b(v);
        if (HASF32) Cf[(long)(rowb + i) * ldcf + col] = v;
      }
    }
  }
}

// ---------------- disease bucketing ----------------
__global__ __launch_bounds__(1024)
void bucket_k(const int* __restrict__ didx, int* __restrict__ perm, int* __restrict__ bstart) {
  __shared__ int cnt[16], base[17], cur[16];
  const int tid = threadIdx.x;
  if (tid < 16) cnt[tid] = 0;
  __syncthreads();
  for (int r = tid; r < 4096; r += 1024) atomicAdd(&cnt[didx[r]], 1);
  __syncthreads();
  if (tid == 0) {
    int s = 0;
    for (int d = 0; d < 16; ++d) { base[d] = s; s += cnt[d]; }
    base[16] = s;
  }
  __syncthreads();
  if (tid < 16) cur[tid] = base[tid];
  if (tid < 17) bstart[tid] = base[tid];
  __syncthreads();
  for (int r = tid; r < 4096; r += 1024) {
    int p = atomicAdd(&cur[didx[r]], 1);
    perm[p] = r;
  }
}

// ---------------- per-disease head GEMM (gathered rows) ----------------
// tile: 64 rows x 256 cols, K=1024, BK=64; grid (64, 16)
__global__ __launch_bounds__(256, 2)
void head_gemm(const short* __restrict__ fused, const short* __restrict__ Wc1T,
               const float* __restrict__ bc1, const int* __restrict__ perm,
               const int* __restrict__ bstart, short* __restrict__ h) {
  const int d = blockIdx.y;
  const int b0 = bstart[d], b1 = bstart[d + 1];
  const int cnt = b1 - b0;
  const int t0 = blockIdx.x << 6;
  if (t0 >= cnt) return;
  __shared__ short lsA[64 * 64];
  __shared__ short lsB[256 * 64];
  const int tid = threadIdx.x, w = tid >> 6, l = tid & 63;
  const int lr = l & 15, lk = (l >> 4) << 3;
  const short* BT = Wc1T + (long)d * (256 * 1024);

  f32x4 acc[4][4];
#pragma unroll
  for (int m = 0; m < 4; ++m)
#pragma unroll
    for (int n = 0; n < 4; ++n) acc[m][n] = (f32x4)0.f;

  const int kc_ = (tid & 7) << 3;
  for (int kt = 0; kt < 1024; kt += 64) {
#pragma unroll
    for (int i = 0; i < 2; ++i) {
      int r = i * 32 + (tid >> 3);                 // 0..63
      int gr = (t0 + r < cnt) ? perm[b0 + t0 + r] : perm[b0];
      gload_lds16(fused + (long)gr * 1024 + kt + kc_, (char*)lsA + (i * 256 + w * 64) * 16);
    }
#pragma unroll
    for (int i = 0; i < 8; ++i) {
      int r = i * 32 + (tid >> 3);                 // 0..255
      gload_lds16(BT + (long)r * 1024 + kt + kc_, (char*)lsB + (i * 256 + w * 64) * 16);
    }
    __syncthreads();
#pragma unroll
    for (int kk = 0; kk < 64; kk += 32) {
      bf16x8 a[4], b[4];
#pragma unroll
      for (int m = 0; m < 4; ++m)
        a[m] = *(const bf16x8*)&lsA[(m * 16 + lr) * 64 + kk + lk];
#pragma unroll
      for (int n = 0; n < 4; ++n)
        b[n] = *(const bf16x8*)&lsB[((w << 6) + n * 16 + lr) * 64 + kk + lk];
#pragma unroll
      for (int m = 0; m < 4; ++m)
#pragma unroll
        for (int n = 0; n < 4; ++n)
          acc[m][n] = __builtin_amdgcn_mfma_f32_16x16x32_bf16(a[m], b[n], acc[m][n], 0, 0, 0);
    }
    __syncthreads();
  }

#pragma unroll
  for (int m = 0; m < 4; ++m)
#pragma unroll
    for (int i2 = 0; i2 < 4; ++i2) {
      const int lrow = m * 16 + ((l >> 4) << 2) + i2;
      if (t0 + lrow >= cnt) continue;
      const int gr = perm[b0 + t0 + lrow];
#pragma unroll
      for (int n = 0; n < 4; ++n) {
        const int col = (w << 6) + n * 16 + lr;
        float v = acc[m][n][i2] + bc1[d * 256 + col];
        v = fmaxf(v, 0.f);
        h[(long)gr * 256 + col] = f2b(v);
      }
    }
}

// ---------------- logits GEMV: one wave per row ----------------
__global__ __launch_bounds__(256)
void logits_k(const short* __restrict__ h, const float* __restrict__ Wc2,
              const float* __restrict__ bc2, const int* __restrict__ didx,
              float* __restrict__ out) {
  const int w = threadIdx.x >> 6, l = threadIdx.x & 63;
  const int r = (blockIdx.x << 2) + w;
  const int d = didx[r];
  const short4 hv4 = *(const short4*)(h + (long)r * 256 + (l << 2));
  const float* wr_ = Wc2 + d * 512 + (l << 3);
  const float4 w01 = *(const float4*)wr_;
  const float4 w23 = *(const float4*)(wr_ + 4);
  const float h0 = b2f(hv4.x), h1 = b2f(hv4.y), h2 = b2f(hv4.z), h3 = b2f(hv4.w);
  float a0 = h0 * w01.x + h1 * w01.z + h2 * w23.x + h3 * w23.z;
  float a1 = h0 * w01.y + h1 * w01.w + h2 * w23.y + h3 * w23.w;
#pragma unroll
  for (int off = 32; off > 0; off >>= 1) {
    a0 += __shfl_down(a0, off);
    a1 += __shfl_down(a1, off);
  }
  if (l == 0) {
    out[r * 2 + 0] = a0 + bc2[d * 2 + 0];
    out[r * 2 + 1] = a1 + bc2[d * 2 + 1];
  }
}

// ---------------- emotion layer-2 GEMV: one wave per row ----------------
__global__ __launch_bounds__(256)
void emo2_k(const short* __restrict__ e1, const float* __restrict__ We2,
            const float* __restrict__ be2, float* __restrict__ out) {
  const int w = threadIdx.x >> 6, l = threadIdx.x & 63;
  const int r = (blockIdx.x << 2) + w;
  const float h0 = b2f(e1[(long)r * 128 + 2 * l]);
  const float h1 = b2f(e1[(long)r * 128 + 2 * l + 1]);
  const float* w0 = We2 + (2 * l) * 8;
  float a[8];
#pragma unroll
  for (int c = 0; c < 8; ++c) a[c] = h0 * w0[c] + h1 * w0[8 + c];
#pragma unroll
  for (int c = 0; c < 8; ++c)
#pragma unroll
    for (int off = 32; off > 0; off >>= 1) a[c] += __shfl_down(a[c], off);
  if (l == 0) {
#pragma unroll
    for (int c = 0; c < 8; ++c) out[r * 8 + c] = a[c] + be2[c];
  }
}

// ---------------- launch ----------------
extern "C" void kernel_launch(void* const* d_in, const int* in_sizes, int n_in,
                              void* d_out, int out_size, void* d_ws, size_t ws_size,
                              hipStream_t stream) {
  const float* audio = (const float*)d_in[0];
  const float* video = (const float*)d_in[1];
  const int*   didx  = (const int*)d_in[2];
  const float* Wa    = (const float*)d_in[3];
  const float* ba    = (const float*)d_in[4];
  const float* Wv    = (const float*)d_in[5];
  const float* bv    = (const float*)d_in[6];
  const float* Pa    = (const float*)d_in[7];
  const float* Cva   = (const float*)d_in[8];
  const float* Pv    = (const float*)d_in[9];
  const float* Cav   = (const float*)d_in[10];
  const float* Wproj = (const float*)d_in[11];
  const float* bproj = (const float*)d_in[12];
  const float* Wf    = (const float*)d_in[13];
  const float* bfv   = (const float*)d_in[14];
  const float* Wc1   = (const float*)d_in[15];
  const float* bc1   = (const float*)d_in[16];
  const float* Wc2   = (const float*)d_in[17];
  const float* bc2   = (const float*)d_in[18];
  const float* We1   = (const float*)d_in[19];
  const float* be1   = (const float*)d_in[20];
  const float* We2   = (const float*)d_in[21];
  const float* be2   = (const float*)d_in[22];

  char* ws = (char*)d_ws;
  short* a_bf   = (short*)(ws + 0);
  short* v_bf   = (short*)(ws + 6291456);
  short* cat    = (short*)(ws + 0);          // aliases a_bf/v_bf (consumed by then)
  short* WaT    = (short*)(ws + 23068672);
  short* WvT    = (short*)(ws + 23855104);
  short* WattT  = (short*)(ws + 25952256);
  short* WprojT = (short*)(ws + 30146560);
  short* WfT    = (short*)(ws + 34340864);
  short* Wc1T   = (short*)(ws + 40632320);
  short* We1T   = (short*)(ws + 49020928);
  short* afvf   = (short*)(ws + 49152000);
  short* fusedA = (short*)(ws + 57540608);
  short* fusedB = (short*)(ws + 65929216);
  short* h_bf   = (short*)(ws + 74317824);
  short* e1_bf  = (short*)(ws + 76414976);
  int*   perm   = (int*)(ws + 77463552);
  int*   bstart = (int*)(ws + 77479936);

  float* out        = (float*)d_out;
  float* out_logits = out;
  float* out_af     = out + 8192;
  float* out_vf     = out + 2105344;
  float* out_fused  = out + 4202496;
  float* out_emo    = out + 8396800;

  // f32 -> bf16 conversions
  conv_k<<<dim3(3072), dim3(256), 0, stream>>>(audio, a_bf, 3145728);
  conv_k<<<dim3(8192), dim3(256), 0, stream>>>(video, v_bf, 8388608);
  // weight transposes (out[n][k] = in[k][n])
  convT_k<<<dim3(16, 24, 1), dim3(256), 0, stream>>>(Wa, WaT, 512, 768, 0, 0);
  convT_k<<<dim3(16, 64, 1), dim3(256), 0, stream>>>(Wv, WvT, 512, 2048, 0, 0);
  convT_k<<<dim3(32, 16, 1), dim3(256), 0, stream>>>(Pa,  WattT, 1024, 1024, 0, 0);
  convT_k<<<dim3(32, 16, 1), dim3(256), 0, stream>>>(Cva, WattT + 512, 1024, 1024, 0, 0);
  convT_k<<<dim3(32, 16, 1), dim3(256), 0, stream>>>(Cav, WattT + 1024 * 1024, 1024, 1024, 0, 0);
  convT_k<<<dim3(32, 16, 1), dim3(256), 0, stream>>>(Pv,  WattT + 1024 * 1024 + 512, 1024, 1024, 0, 0);
  convT_k<<<dim3(32, 64, 1), dim3(256), 0, stream>>>(Wproj, WprojT, 1024, 2048, 0, 0);
  convT_k<<<dim3(32, 32, 3), dim3(256), 0, stream>>>(Wf, WfT, 1024, 1024, 1048576, 1048576);
  convT_k<<<dim3(8, 32, 16), dim3(256), 0, stream>>>(Wc1, Wc1T, 256, 1024, 262144, 262144);
  convT_k<<<dim3(4, 16, 1), dim3(256), 0, stream>>>(We1, We1T, 128, 512, 0, 0);

  // G1: af = relu(audio@Wa+ba) -> afvf[:, :512] (bf16) + out_af (f32)
  gemm_bt<true, true><<<dim3(32, 4), dim3(256), 0, stream>>>(
      a_bf, WaT, ba, afvf, 1024, out_af, 512, 768, 768, 768);
  // G2: vf -> afvf[:, 512:] + out_vf
  gemm_bt<true, true><<<dim3(32, 4), dim3(256), 0, stream>>>(
      v_bf, WvT, bv, afvf + 512, 1024, out_vf, 512, 2048, 2048, 2048);
  // G3: cat = afvf @ W_att  (both attended streams at once)
  gemm_bt<false, false><<<dim3(32, 16), dim3(256), 0, stream>>>(
      afvf, WattT, nullptr, cat, 2048, nullptr, 0, 1024, 1024, 1024);
  // G4: fusedA = cat @ Wproj + bproj  (no relu)
  gemm_bt<false, false><<<dim3(32, 8), dim3(256), 0, stream>>>(
      cat, WprojT, bproj, fusedA, 1024, nullptr, 0, 2048, 2048, 2048);
  // G5..G7: MLP
  gemm_bt<true, false><<<dim3(32, 8), dim3(256), 0, stream>>>(
      fusedA, WfT, bfv, fusedB, 1024, nullptr, 0, 1024, 1024, 1024);
  gemm_bt<true, false><<<dim3(32, 8), dim3(256), 0, stream>>>(
      fusedB, WfT + 1048576, bfv + 1024, fusedA, 1024, nullptr, 0, 1024, 1024, 1024);
  gemm_bt<true, true><<<dim3(32, 8), dim3(256), 0, stream>>>(
      fusedA, WfT + 2097152, bfv + 2048, fusedB, 1024, out_fused, 1024, 1024, 1024, 1024);
  // emotion layer 1: e1 = relu(vf@We1+be1)
  gemm_bt<true, false><<<dim3(32, 1), dim3(256), 0, stream>>>(
      afvf + 512, We1T, be1, e1_bf, 128, nullptr, 0, 512, 1024, 512);

  // heads
  bucket_k<<<dim3(1), dim3(1024), 0, stream>>>(didx, perm, bstart);
  head_gemm<<<dim3(64, 16), dim3(256), 0, stream>>>(fusedB, Wc1T, bc1, perm, bstart, h_bf);
  logits_k<<<dim3(1024), dim3(256), 0, stream>>>(h_bf, Wc2, bc2, didx, out_logits);
  emo2_k<<<dim3(1024), dim3(256), 0, stream>>>(e1_bf, We2, be2, out_emo);
}

// Round 3
// 264.465 us; speedup vs baseline: 1.2043x; 1.2043x over previous
//
#include <hip/hip_runtime.h>
#include <hip/hip_bf16.h>
#include <stdint.h>

// Sizes (fixed): B=4096, A=768, V=2048, H=512, F=1024, ND=16, NC=2, NE=8, NL=3

typedef __attribute__((ext_vector_type(8))) short bf16x8;
typedef __attribute__((ext_vector_type(4))) float f32x4;

__device__ inline short f2b(float f) {
  union { float f; uint32_t u; } a; a.f = f;
  uint32_t r = a.u + 0x7fffu + ((a.u >> 16) & 1u);   // RNE
  return (short)(r >> 16);
}
__device__ inline float b2f(short s) {
  union { uint32_t u; float f; } a; a.u = ((uint32_t)(uint16_t)s) << 16;
  return a.f;
}
__device__ inline void gload_lds16(const void* g, void* l) {
  __builtin_amdgcn_global_load_lds(
      (const __attribute__((address_space(1))) uint32_t*)g,
      (__attribute__((address_space(3))) uint32_t*)l, 16, 0, 0);
}

// ---------------- conversions ----------------
__global__ __launch_bounds__(256)
void conv_k(const float* __restrict__ in, short* __restrict__ out, int n) {
  int i = (blockIdx.x * 256 + threadIdx.x) << 2;
  if (i >= n) return;
  float4 v = *(const float4*)(in + i);
  short4 o; o.x = f2b(v.x); o.y = f2b(v.y); o.z = f2b(v.z); o.w = f2b(v.w);
  *(short4*)(out + i) = o;
}

// out[n*ldout + k] = bf16(in[k*N + n]); grid (N/32, K/32, batch)
__global__ __launch_bounds__(256)
void convT_k(const float* __restrict__ in, short* __restrict__ out,
             int N, int ldout, long instride, long outstride) {
  in  += (long)blockIdx.z * instride;
  out += (long)blockIdx.z * outstride;
  __shared__ float t[32][33];
  const int tx = threadIdx.x & 31, ty = threadIdx.x >> 5;  // 32 x 8
  const int n0 = blockIdx.x << 5, k0 = blockIdx.y << 5;
#pragma unroll
  for (int i = 0; i < 4; ++i)
    t[ty + 8 * i][tx] = in[(long)(k0 + ty + 8 * i) * N + n0 + tx];
  __syncthreads();
#pragma unroll
  for (int i = 0; i < 4; ++i)
    out[(long)(n0 + ty + 8 * i) * ldout + k0 + tx] = f2b(t[tx][ty + 8 * i]);
}

// ---------------- templated GEMM body: C = A(MxK) * BT(NxK)^T ----------------
// 4 waves as 2x2; per-wave (BM/2)x(BN/2); BK=64; 16x16x32 MFMA.
// LDS staging: each gload_lds16 call writes (per wave) 64 lanes x 16B = 1024B;
// each 32-row x 64-col bf16 chunk = 4096B.
template<int BM, int BN, bool RELU, bool HASF32>
__device__ __forceinline__
void gemm_body(const short* __restrict__ A, const short* __restrict__ BT,
               const float* __restrict__ bias,
               short* __restrict__ Cb, int ldcb,
               float* __restrict__ Cf, int ldcf,
               int K, int lda, int ldbt, int m0, int n0,
               short* lsA, short* lsB) {
  constexpr int MR = BM / 32, NR = BN / 32;
  const int tid = threadIdx.x;
  const int w = tid >> 6, l = tid & 63;
  const int wr = w >> 1, wc = w & 1;
  const int lr = l & 15, lk = (l >> 4) << 3;

  f32x4 acc[MR][NR];
#pragma unroll
  for (int m = 0; m < MR; ++m)
#pragma unroll
    for (int n = 0; n < NR; ++n) acc[m][n] = (f32x4)0.f;

  const int r_ = tid >> 3;            // 0..31
  const int kc_ = (tid & 7) << 3;     // 0..56
  const short* Arow = A + (long)(m0 + r_) * lda + kc_;
  const short* Brow = BT + (long)(n0 + r_) * ldbt + kc_;

  for (int kt = 0; kt < K; kt += 64) {
#pragma unroll
    for (int i = 0; i < BM / 32; ++i)
      gload_lds16(Arow + (long)i * 32 * lda + kt, (char*)lsA + i * 4096 + w * 1024);
#pragma unroll
    for (int i = 0; i < BN / 32; ++i)
      gload_lds16(Brow + (long)i * 32 * ldbt + kt, (char*)lsB + i * 4096 + w * 1024);
    __syncthreads();
#pragma unroll
    for (int kk = 0; kk < 64; kk += 32) {
      bf16x8 a[MR], b[NR];
#pragma unroll
      for (int m = 0; m < MR; ++m)
        a[m] = *(const bf16x8*)&lsA[(wr * (BM / 2) + m * 16 + lr) * 64 + kk + lk];
#pragma unroll
      for (int n = 0; n < NR; ++n)
        b[n] = *(const bf16x8*)&lsB[(wc * (BN / 2) + n * 16 + lr) * 64 + kk + lk];
#pragma unroll
      for (int m = 0; m < MR; ++m)
#pragma unroll
        for (int n = 0; n < NR; ++n)
          acc[m][n] = __builtin_amdgcn_mfma_f32_16x16x32_bf16(a[m], b[n], acc[m][n], 0, 0, 0);
    }
    __syncthreads();
  }

  const int lrow = (l >> 4) << 2;
#pragma unroll
  for (int n = 0; n < NR; ++n) {
    const int col = n0 + wc * (BN / 2) + n * 16 + lr;
    const float bz = bias ? bias[col] : 0.f;
#pragma unroll
    for (int m = 0; m < MR; ++m) {
      const int rowb = m0 + wr * (BM / 2) + m * 16 + lrow;
#pragma unroll
      for (int i = 0; i < 4; ++i) {
        float v = acc[m][n][i] + bz;
        if (RELU) v = fmaxf(v, 0.f);
        Cb[(long)(rowb + i) * ldcb + col] = f2b(v);
        if (HASF32) Cf[(long)(rowb + i) * ldcf + col] = v;
      }
    }
  }
}

template<int BM, int BN, bool RELU, bool HASF32>
__global__ __launch_bounds__(256, 2)
void gemm_bt(const short* __restrict__ A, const short* __restrict__ BT,
             const float* __restrict__ bias,
             short* __restrict__ Cb, int ldcb,
             float* __restrict__ Cf, int ldcf,
             int K, int lda, int ldbt) {
  __shared__ short lsA[BM * 64];
  __shared__ short lsB[BN * 64];
  gemm_body<BM, BN, RELU, HASF32>(A, BT, bias, Cb, ldcb, Cf, ldcf,
                                  K, lda, ldbt, blockIdx.x * BM, blockIdx.y * BN,
                                  lsA, lsB);
}

// Fused audio+video encoder: blockIdx.y<8 -> audio GEMM, else video GEMM.
__global__ __launch_bounds__(256, 2)
void enc_gemm(const short* __restrict__ a_bf, const short* __restrict__ v_bf,
              const short* __restrict__ WaT, const short* __restrict__ WvT,
              const float* __restrict__ ba, const float* __restrict__ bv,
              short* __restrict__ afvf, float* __restrict__ out_af,
              float* __restrict__ out_vf) {
  __shared__ short lsA[128 * 64];
  __shared__ short lsB[64 * 64];
  const bool isA = blockIdx.y < 8;
  gemm_body<128, 64, true, true>(
      isA ? a_bf : v_bf, isA ? WaT : WvT, isA ? ba : bv,
      afvf + (isA ? 0 : 512), 1024, isA ? out_af : out_vf, 512,
      isA ? 768 : 2048, isA ? 768 : 2048, isA ? 768 : 2048,
      blockIdx.x * 128, (blockIdx.y & 7) * 64, lsA, lsB);
}

// ---------------- disease bucketing + block map ----------------
__global__ __launch_bounds__(1024)
void bucket_k(const int* __restrict__ didx, int* __restrict__ perm,
              int* __restrict__ bstart, int* __restrict__ bmap) {
  __shared__ int cnt[16], base[17], cur[16];
  const int tid = threadIdx.x;
  if (tid < 16) cnt[tid] = 0;
  __syncthreads();
  for (int r = tid; r < 4096; r += 1024) atomicAdd(&cnt[didx[r]], 1);
  __syncthreads();
  if (tid == 0) {
    int s = 0;
    for (int d = 0; d < 16; ++d) { base[d] = s; s += cnt[d]; }
    base[16] = s;
    int nb = 0;
    for (int d = 0; d < 16; ++d) {
      int nblk = (cnt[d] + 63) >> 6;
      for (int i = 0; i < nblk; ++i) bmap[nb++] = (d << 8) | i;
    }
    bstart[17] = nb;
  }
  __syncthreads();
  if (tid < 16) cur[tid] = base[tid];
  if (tid < 17) bstart[tid] = base[tid];
  __syncthreads();
  for (int r = tid; r < 4096; r += 1024) {
    int p = atomicAdd(&cur[didx[r]], 1);
    perm[p] = r;
  }
}

// ---------------- per-disease head GEMM (gathered rows) ----------------
// 64x64 tiles; grid (80, 4): x = flat (disease,rowtile) via bmap, y = col tile.
__global__ __launch_bounds__(256, 2)
void head_gemm(const short* __restrict__ fused, const short* __restrict__ Wc1T,
               const float* __restrict__ bc1, const int* __restrict__ perm,
               const int* __restrict__ bstart, const int* __restrict__ bmap,
               short* __restrict__ h) {
  const int nb = bstart[17];
  if ((int)blockIdx.x >= nb) return;
  const int me = bmap[blockIdx.x];
  const int d = me >> 8, rt = me & 0xff;
  const int b0 = bstart[d], cnt = bstart[d + 1] - b0;
  const int t0 = rt << 6;
  const int c0 = blockIdx.y << 6;
  __shared__ short lsA[64 * 64];
  __shared__ short lsB[64 * 64];
  const int tid = threadIdx.x, w = tid >> 6, l = tid & 63;
  const int wr = w >> 1, wc = w & 1;
  const int lr = l & 15, lk = (l >> 4) << 3;
  const short* BT = Wc1T + (long)d * (256 * 1024) + (long)c0 * 1024;

  f32x4 acc[2][2];
#pragma unroll
  for (int m = 0; m < 2; ++m)
#pragma unroll
    for (int n = 0; n < 2; ++n) acc[m][n] = (f32x4)0.f;

  const int r_ = tid >> 3, kc_ = (tid & 7) << 3;
  // gathered A row pointers (clamped for padding rows)
  int gr0 = (t0 + r_      < cnt) ? perm[b0 + t0 + r_]      : perm[b0];
  int gr1 = (t0 + r_ + 32 < cnt) ? perm[b0 + t0 + r_ + 32] : perm[b0];
  const short* A0 = fused + (long)gr0 * 1024 + kc_;
  const short* A1 = fused + (long)gr1 * 1024 + kc_;
  const short* Brow = BT + (long)r_ * 1024 + kc_;

  for (int kt = 0; kt < 1024; kt += 64) {
    gload_lds16(A0 + kt, (char*)lsA + w * 1024);
    gload_lds16(A1 + kt, (char*)lsA + 4096 + w * 1024);
    gload_lds16(Brow + kt, (char*)lsB + w * 1024);
    gload_lds16(Brow + 32 * 1024 + kt, (char*)lsB + 4096 + w * 1024);
    __syncthreads();
#pragma unroll
    for (int kk = 0; kk < 64; kk += 32) {
      bf16x8 a[2], b[2];
#pragma unroll
      for (int m = 0; m < 2; ++m)
        a[m] = *(const bf16x8*)&lsA[(wr * 32 + m * 16 + lr) * 64 + kk + lk];
#pragma unroll
      for (int n = 0; n < 2; ++n)
        b[n] = *(const bf16x8*)&lsB[(wc * 32 + n * 16 + lr) * 64 + kk + lk];
#pragma unroll
      for (int m = 0; m < 2; ++m)
#pragma unroll
        for (int n = 0; n < 2; ++n)
          acc[m][n] = __builtin_amdgcn_mfma_f32_16x16x32_bf16(a[m], b[n], acc[m][n], 0, 0, 0);
    }
    __syncthreads();
  }

#pragma unroll
  for (int m = 0; m < 2; ++m)
#pragma unroll
    for (int i2 = 0; i2 < 4; ++i2) {
      const int lrow = wr * 32 + m * 16 + ((l >> 4) << 2) + i2;
      if (t0 + lrow >= cnt) continue;
      const int gr = perm[b0 + t0 + lrow];
#pragma unroll
      for (int n = 0; n < 2; ++n) {
        const int col = c0 + wc * 32 + n * 16 + lr;
        float v = acc[m][n][i2] + bc1[d * 256 + col];
        v = fmaxf(v, 0.f);
        h[(long)gr * 256 + col] = f2b(v);
      }
    }
}

// ---------------- logits GEMV: one wave per row ----------------
__global__ __launch_bounds__(256)
void logits_k(const short* __restrict__ h, const float* __restrict__ Wc2,
              const float* __restrict__ bc2, const int* __restrict__ didx,
              float* __restrict__ out) {
  const int w = threadIdx.x >> 6, l = threadIdx.x & 63;
  const int r = (blockIdx.x << 2) + w;
  const int d = didx[r];
  const short4 hv4 = *(const short4*)(h + (long)r * 256 + (l << 2));
  const float* wr_ = Wc2 + d * 512 + (l << 3);
  const float4 w01 = *(const float4*)wr_;
  const float4 w23 = *(const float4*)(wr_ + 4);
  const float h0 = b2f(hv4.x), h1 = b2f(hv4.y), h2 = b2f(hv4.z), h3 = b2f(hv4.w);
  float a0 = h0 * w01.x + h1 * w01.z + h2 * w23.x + h3 * w23.z;
  float a1 = h0 * w01.y + h1 * w01.w + h2 * w23.y + h3 * w23.w;
#pragma unroll
  for (int off = 32; off > 0; off >>= 1) {
    a0 += __shfl_down(a0, off);
    a1 += __shfl_down(a1, off);
  }
  if (l == 0) {
    out[r * 2 + 0] = a0 + bc2[d * 2 + 0];
    out[r * 2 + 1] = a1 + bc2[d * 2 + 1];
  }
}

// ---------------- emotion layer-2 GEMV: one wave per row ----------------
__global__ __launch_bounds__(256)
void emo2_k(const short* __restrict__ e1, const float* __restrict__ We2,
            const float* __restrict__ be2, float* __restrict__ out) {
  const int w = threadIdx.x >> 6, l = threadIdx.x & 63;
  const int r = (blockIdx.x << 2) + w;
  const float h0 = b2f(e1[(long)r * 128 + 2 * l]);
  const float h1 = b2f(e1[(long)r * 128 + 2 * l + 1]);
  const float* w0 = We2 + (2 * l) * 8;
  float a[8];
#pragma unroll
  for (int c = 0; c < 8; ++c) a[c] = h0 * w0[c] + h1 * w0[8 + c];
#pragma unroll
  for (int c = 0; c < 8; ++c)
#pragma unroll
    for (int off = 32; off > 0; off >>= 1) a[c] += __shfl_down(a[c], off);
  if (l == 0) {
#pragma unroll
    for (int c = 0; c < 8; ++c) out[r * 8 + c] = a[c] + be2[c];
  }
}

// ---------------- launch ----------------
extern "C" void kernel_launch(void* const* d_in, const int* in_sizes, int n_in,
                              void* d_out, int out_size, void* d_ws, size_t ws_size,
                              hipStream_t stream) {
  const float* audio = (const float*)d_in[0];
  const float* video = (const float*)d_in[1];
  const int*   didx  = (const int*)d_in[2];
  const float* Wa    = (const float*)d_in[3];
  const float* ba    = (const float*)d_in[4];
  const float* Wv    = (const float*)d_in[5];
  const float* bv    = (const float*)d_in[6];
  const float* Pa    = (const float*)d_in[7];
  const float* Cva   = (const float*)d_in[8];
  const float* Pv    = (const float*)d_in[9];
  const float* Cav   = (const float*)d_in[10];
  const float* Wproj = (const float*)d_in[11];
  const float* bproj = (const float*)d_in[12];
  const float* Wf    = (const float*)d_in[13];
  const float* bfv   = (const float*)d_in[14];
  const float* Wc1   = (const float*)d_in[15];
  const float* bc1   = (const float*)d_in[16];
  const float* Wc2   = (const float*)d_in[17];
  const float* bc2   = (const float*)d_in[18];
  const float* We1   = (const float*)d_in[19];
  const float* be1   = (const float*)d_in[20];
  const float* We2   = (const float*)d_in[21];
  const float* be2   = (const float*)d_in[22];

  char* ws = (char*)d_ws;
  short* a_bf   = (short*)(ws + 0);
  short* v_bf   = (short*)(ws + 6291456);
  short* cat    = (short*)(ws + 0);          // aliases a_bf/v_bf (consumed by then)
  short* WaT    = (short*)(ws + 23068672);
  short* WvT    = (short*)(ws + 23855104);
  short* WattT  = (short*)(ws + 25952256);
  short* WprojT = (short*)(ws + 30146560);
  short* WfT    = (short*)(ws + 34340864);
  short* Wc1T   = (short*)(ws + 40632320);
  short* We1T   = (short*)(ws + 49020928);
  short* afvf   = (short*)(ws + 49152000);
  short* fusedA = (short*)(ws + 57540608);
  short* fusedB = (short*)(ws + 65929216);
  short* h_bf   = (short*)(ws + 74317824);
  short* e1_bf  = (short*)(ws + 76414976);
  int*   perm   = (int*)(ws + 77463552);
  int*   bstart = (int*)(ws + 77479936);     // 18 ints
  int*   bmap   = (int*)(ws + 77480064);     // 128 ints

  float* out        = (float*)d_out;
  float* out_logits = out;
  float* out_af     = out + 8192;
  float* out_vf     = out + 2105344;
  float* out_fused  = out + 4202496;
  float* out_emo    = out + 8396800;

  // f32 -> bf16 conversions
  conv_k<<<dim3(3072), dim3(256), 0, stream>>>(audio, a_bf, 3145728);
  conv_k<<<dim3(8192), dim3(256), 0, stream>>>(video, v_bf, 8388608);
  // weight transposes (out[n][k] = in[k][n])
  convT_k<<<dim3(16, 24, 1), dim3(256), 0, stream>>>(Wa, WaT, 512, 768, 0, 0);
  convT_k<<<dim3(16, 64, 1), dim3(256), 0, stream>>>(Wv, WvT, 512, 2048, 0, 0);
  convT_k<<<dim3(32, 16, 1), dim3(256), 0, stream>>>(Pa,  WattT, 1024, 1024, 0, 0);
  convT_k<<<dim3(32, 16, 1), dim3(256), 0, stream>>>(Cva, WattT + 512, 1024, 1024, 0, 0);
  convT_k<<<dim3(32, 16, 1), dim3(256), 0, stream>>>(Cav, WattT + 1024 * 1024, 1024, 1024, 0, 0);
  convT_k<<<dim3(32, 16, 1), dim3(256), 0, stream>>>(Pv,  WattT + 1024 * 1024 + 512, 1024, 1024, 0, 0);
  convT_k<<<dim3(32, 64, 1), dim3(256), 0, stream>>>(Wproj, WprojT, 1024, 2048, 0, 0);
  convT_k<<<dim3(32, 32, 3), dim3(256), 0, stream>>>(Wf, WfT, 1024, 1024, 1048576, 1048576);
  convT_k<<<dim3(8, 32, 16), dim3(256), 0, stream>>>(Wc1, Wc1T, 256, 1024, 262144, 262144);
  convT_k<<<dim3(4, 16, 1), dim3(256), 0, stream>>>(We1, We1T, 128, 512, 0, 0);

  // bucketing early (independent of GEMM chain)
  bucket_k<<<dim3(1), dim3(1024), 0, stream>>>(didx, perm, bstart, bmap);

  // G1+G2 fused: af|vf = relu([audio,video] @ [Wa,Wv] + b) -> afvf + f32 outs
  enc_gemm<<<dim3(32, 16), dim3(256), 0, stream>>>(
      a_bf, v_bf, WaT, WvT, ba, bv, afvf, out_af, out_vf);
  // G3: cat = afvf @ W_att  (both attended streams at once)
  gemm_bt<128, 128, false, false><<<dim3(32, 16), dim3(256), 0, stream>>>(
      afvf, WattT, nullptr, cat, 2048, nullptr, 0, 1024, 1024, 1024);
  // G4: fusedA = cat @ Wproj + bproj  (no relu)
  gemm_bt<128, 128, false, false><<<dim3(32, 8), dim3(256), 0, stream>>>(
      cat, WprojT, bproj, fusedA, 1024, nullptr, 0, 2048, 2048, 2048);
  // G5..G7: MLP
  gemm_bt<128, 128, true, false><<<dim3(32, 8), dim3(256), 0, stream>>>(
      fusedA, WfT, bfv, fusedB, 1024, nullptr, 0, 1024, 1024, 1024);
  gemm_bt<128, 128, true, false><<<dim3(32, 8), dim3(256), 0, stream>>>(
      fusedB, WfT + 1048576, bfv + 1024, fusedA, 1024, nullptr, 0, 1024, 1024, 1024);
  gemm_bt<128, 128, true, true><<<dim3(32, 8), dim3(256), 0, stream>>>(
      fusedA, WfT + 2097152, bfv + 2048, fusedB, 1024, out_fused, 1024, 1024, 1024, 1024);
  // emotion layer 1: e1 = relu(vf@We1+be1)  (64x64 tiles -> 128 blocks)
  gemm_bt<64, 64, true, false><<<dim3(64, 2), dim3(256), 0, stream>>>(
      afvf + 512, We1T, be1, e1_bf, 128, nullptr, 0, 512, 1024, 512);

  // heads
  head_gemm<<<dim3(80, 4), dim3(256), 0, stream>>>(fusedB, Wc1T, bc1, perm, bstart, bmap, h_bf);
  logits_k<<<dim3(1024), dim3(256), 0, stream>>>(h_bf, Wc2, bc2, didx, out_logits);
  emo2_k<<<dim3(1024), dim3(256), 0, stream>>>(e1_bf, We2, be2, out_emo);
}

// Round 4
// 222.737 us; speedup vs baseline: 1.4299x; 1.1873x over previous
//
#include <hip/hip_runtime.h>
#include <hip/hip_bf16.h>
#include <stdint.h>

// Sizes (fixed): B=4096, A=768, V=2048, H=512, F=1024, ND=16, NC=2, NE=8, NL=3

typedef __attribute__((ext_vector_type(8))) short bf16x8;
typedef __attribute__((ext_vector_type(4))) float f32x4;

__device__ inline short f2b(float f) {
  union { float f; uint32_t u; } a; a.f = f;
  uint32_t r = a.u + 0x7fffu + ((a.u >> 16) & 1u);   // RNE
  return (short)(r >> 16);
}
__device__ inline float b2f(short s) {
  union { uint32_t u; float f; } a; a.u = ((uint32_t)(uint16_t)s) << 16;
  return a.f;
}
__device__ inline void gload_lds16(const void* g, void* l) {
  __builtin_amdgcn_global_load_lds(
      (const __attribute__((address_space(1))) uint32_t*)g,
      (__attribute__((address_space(3))) uint32_t*)l, 16, 0, 0);
}

// ---------------- conversions ----------------
__global__ __launch_bounds__(256)
void conv_k(const float* __restrict__ in, short* __restrict__ out, int n) {
  int i = (blockIdx.x * 256 + threadIdx.x) << 2;
  if (i >= n) return;
  float4 v = *(const float4*)(in + i);
  short4 o; o.x = f2b(v.x); o.y = f2b(v.y); o.z = f2b(v.z); o.w = f2b(v.w);
  *(short4*)(out + i) = o;
}

// out[n*ldout + k] = bf16(in[k*N + n]); grid (N/32, K/32, batch)
__global__ __launch_bounds__(256)
void convT_k(const float* __restrict__ in, short* __restrict__ out,
             int N, int ldout, long instride, long outstride) {
  in  += (long)blockIdx.z * instride;
  out += (long)blockIdx.z * outstride;
  __shared__ float t[32][33];
  const int tx = threadIdx.x & 31, ty = threadIdx.x >> 5;  // 32 x 8
  const int n0 = blockIdx.x << 5, k0 = blockIdx.y << 5;
#pragma unroll
  for (int i = 0; i < 4; ++i)
    t[ty + 8 * i][tx] = in[(long)(k0 + ty + 8 * i) * N + n0 + tx];
  __syncthreads();
#pragma unroll
  for (int i = 0; i < 4; ++i)
    out[(long)(n0 + ty + 8 * i) * ldout + k0 + tx] = f2b(t[tx][ty + 8 * i]);
}

// Build Watt_rm (1024 x 2048 bf16, row-major) = [[Pa, Cav],[Cva, Pv]].
// grid (512, 4): blockIdx.x = row within 512-block; y selects source block.
__global__ __launch_bounds__(256)
void conv4_k(const float* __restrict__ Pa, const float* __restrict__ Cva,
             const float* __restrict__ Cav, const float* __restrict__ Pv,
             short* __restrict__ Watt) {
  const int h = blockIdx.x, q = blockIdx.y;
  const float* src; int rowoff, coloff;
  if (q == 0)      { src = Pa;  rowoff = 0;   coloff = 0; }
  else if (q == 1) { src = Cav; rowoff = 0;   coloff = 1024; }
  else if (q == 2) { src = Cva; rowoff = 512; coloff = 0; }
  else             { src = Pv;  rowoff = 512; coloff = 1024; }
  const int j = threadIdx.x << 2;
  float4 v = *(const float4*)(src + (long)h * 1024 + j);
  short4 o; o.x = f2b(v.x); o.y = f2b(v.y); o.z = f2b(v.z); o.w = f2b(v.w);
  *(short4*)(Watt + (long)(rowoff + h) * 2048 + coloff + j) = o;
}

// ---------------- templated GEMM body: C = A(MxK) * BT(NxK)^T ----------------
// 4 waves as 2x2; per-wave (BM/2)x(BN/2); BK=64; 16x16x32 MFMA.
// LDS staging: each gload_lds16 writes (per wave) 64 lanes x 16B = 1024B;
// each 32-row x 64-col bf16 chunk = 4096B.
template<int BM, int BN, bool RELU, bool HASF32>
__device__ __forceinline__
void gemm_body(const short* __restrict__ A, const short* __restrict__ BT,
               const float* __restrict__ bias,
               short* __restrict__ Cb, int ldcb,
               float* __restrict__ Cf, int ldcf,
               int K, int lda, int ldbt, int m0, int n0,
               short* lsA, short* lsB) {
  constexpr int MR = BM / 32, NR = BN / 32;
  const int tid = threadIdx.x;
  const int w = tid >> 6, l = tid & 63;
  const int wr = w >> 1, wc = w & 1;
  const int lr = l & 15, lk = (l >> 4) << 3;

  f32x4 acc[MR][NR];
#pragma unroll
  for (int m = 0; m < MR; ++m)
#pragma unroll
    for (int n = 0; n < NR; ++n) acc[m][n] = (f32x4)0.f;

  const int r_ = tid >> 3;            // 0..31
  const int kc_ = (tid & 7) << 3;     // 0..56
  const short* Arow = A + (long)(m0 + r_) * lda + kc_;
  const short* Brow = BT + (long)(n0 + r_) * ldbt + kc_;

  for (int kt = 0; kt < K; kt += 64) {
#pragma unroll
    for (int i = 0; i < BM / 32; ++i)
      gload_lds16(Arow + (long)i * 32 * lda + kt, (char*)lsA + i * 4096 + w * 1024);
#pragma unroll
    for (int i = 0; i < BN / 32; ++i)
      gload_lds16(Brow + (long)i * 32 * ldbt + kt, (char*)lsB + i * 4096 + w * 1024);
    __syncthreads();
#pragma unroll
    for (int kk = 0; kk < 64; kk += 32) {
      bf16x8 a[MR], b[NR];
#pragma unroll
      for (int m = 0; m < MR; ++m)
        a[m] = *(const bf16x8*)&lsA[(wr * (BM / 2) + m * 16 + lr) * 64 + kk + lk];
#pragma unroll
      for (int n = 0; n < NR; ++n)
        b[n] = *(const bf16x8*)&lsB[(wc * (BN / 2) + n * 16 + lr) * 64 + kk + lk];
#pragma unroll
      for (int m = 0; m < MR; ++m)
#pragma unroll
        for (int n = 0; n < NR; ++n)
          acc[m][n] = __builtin_amdgcn_mfma_f32_16x16x32_bf16(a[m], b[n], acc[m][n], 0, 0, 0);
    }
    __syncthreads();
  }

  const int lrow = (l >> 4) << 2;
#pragma unroll
  for (int n = 0; n < NR; ++n) {
    const int col = n0 + wc * (BN / 2) + n * 16 + lr;
    const float bz = bias ? bias[col] : 0.f;
#pragma unroll
    for (int m = 0; m < MR; ++m) {
      const int rowb = m0 + wr * (BM / 2) + m * 16 + lrow;
#pragma unroll
      for (int i = 0; i < 4; ++i) {
        float v = acc[m][n][i] + bz;
        if (RELU) v = fmaxf(v, 0.f);
        Cb[(long)(rowb + i) * ldcb + col] = f2b(v);
        if (HASF32) Cf[(long)(rowb + i) * ldcf + col] = v;
      }
    }
  }
}

template<int BM, int BN, bool RELU, bool HASF32>
__global__ __launch_bounds__(256, 2)
void gemm_bt(const short* __restrict__ A, const short* __restrict__ BT,
             const float* __restrict__ bias,
             short* __restrict__ Cb, int ldcb,
             float* __restrict__ Cf, int ldcf,
             int K, int lda, int ldbt) {
  __shared__ short lsA[BM * 64];
  __shared__ short lsB[BN * 64];
  gemm_body<BM, BN, RELU, HASF32>(A, BT, bias, Cb, ldcb, Cf, ldcf,
                                  K, lda, ldbt, blockIdx.x * BM, blockIdx.y * BN,
                                  lsA, lsB);
}

// Fused audio+video encoder: blockIdx.y<8 -> audio GEMM, else video GEMM.
__global__ __launch_bounds__(256, 2)
void enc_gemm(const short* __restrict__ a_bf, const short* __restrict__ v_bf,
              const short* __restrict__ WaT, const short* __restrict__ WvT,
              const float* __restrict__ ba, const float* __restrict__ bv,
              short* __restrict__ afvf, float* __restrict__ out_af,
              float* __restrict__ out_vf) {
  __shared__ short lsA[128 * 64];
  __shared__ short lsB[64 * 64];
  const bool isA = blockIdx.y < 8;
  gemm_body<128, 64, true, true>(
      isA ? a_bf : v_bf, isA ? WaT : WvT, isA ? ba : bv,
      afvf + (isA ? 0 : 512), 1024, isA ? out_af : out_vf, 512,
      isA ? 768 : 2048, isA ? 768 : 2048, isA ? 768 : 2048,
      blockIdx.x * 128, (blockIdx.y & 7) * 64, lsA, lsB);
}

// ---------------- disease bucketing + block map ----------------
__global__ __launch_bounds__(1024)
void bucket_k(const int* __restrict__ didx, int* __restrict__ perm,
              int* __restrict__ bstart, int* __restrict__ bmap) {
  __shared__ int cnt[16], base[17], cur[16];
  const int tid = threadIdx.x;
  if (tid < 16) cnt[tid] = 0;
  __syncthreads();
  for (int r = tid; r < 4096; r += 1024) atomicAdd(&cnt[didx[r]], 1);
  __syncthreads();
  if (tid == 0) {
    int s = 0;
    for (int d = 0; d < 16; ++d) { base[d] = s; s += cnt[d]; }
    base[16] = s;
    int nb = 0;
    for (int d = 0; d < 16; ++d) {
      int nblk = (cnt[d] + 63) >> 6;
      for (int i = 0; i < nblk; ++i) bmap[nb++] = (d << 8) | i;
    }
    bstart[17] = nb;
  }
  __syncthreads();
  if (tid < 16) cur[tid] = base[tid];
  if (tid < 17) bstart[tid] = base[tid];
  __syncthreads();
  for (int r = tid; r < 4096; r += 1024) {
    int p = atomicAdd(&cur[didx[r]], 1);
    perm[p] = r;
  }
}

// ---------------- per-disease head GEMM (gathered rows) ----------------
// 64x64 tiles; grid (80, 4): x = flat (disease,rowtile) via bmap, y = col tile.
__global__ __launch_bounds__(256, 2)
void head_gemm(const short* __restrict__ fused, const short* __restrict__ Wc1T,
               const float* __restrict__ bc1, const int* __restrict__ perm,
               const int* __restrict__ bstart, const int* __restrict__ bmap,
               short* __restrict__ h) {
  const int nb = bstart[17];
  if ((int)blockIdx.x >= nb) return;
  const int me = bmap[blockIdx.x];
  const int d = me >> 8, rt = me & 0xff;
  const int b0 = bstart[d], cnt = bstart[d + 1] - b0;
  const int t0 = rt << 6;
  const int c0 = blockIdx.y << 6;
  __shared__ short lsA[64 * 64];
  __shared__ short lsB[64 * 64];
  const int tid = threadIdx.x, w = tid >> 6, l = tid & 63;
  const int wr = w >> 1, wc = w & 1;
  const int lr = l & 15, lk = (l >> 4) << 3;
  const short* BT = Wc1T + (long)d * (256 * 1024) + (long)c0 * 1024;

  f32x4 acc[2][2];
#pragma unroll
  for (int m = 0; m < 2; ++m)
#pragma unroll
    for (int n = 0; n < 2; ++n) acc[m][n] = (f32x4)0.f;

  const int r_ = tid >> 3, kc_ = (tid & 7) << 3;
  // gathered A row pointers (clamped for padding rows)
  int gr0 = (t0 + r_      < cnt) ? perm[b0 + t0 + r_]      : perm[b0];
  int gr1 = (t0 + r_ + 32 < cnt) ? perm[b0 + t0 + r_ + 32] : perm[b0];
  const short* A0 = fused + (long)gr0 * 1024 + kc_;
  const short* A1 = fused + (long)gr1 * 1024 + kc_;
  const short* Brow = BT + (long)r_ * 1024 + kc_;

  for (int kt = 0; kt < 1024; kt += 64) {
    gload_lds16(A0 + kt, (char*)lsA + w * 1024);
    gload_lds16(A1 + kt, (char*)lsA + 4096 + w * 1024);
    gload_lds16(Brow + kt, (char*)lsB + w * 1024);
    gload_lds16(Brow + 32 * 1024 + kt, (char*)lsB + 4096 + w * 1024);
    __syncthreads();
#pragma unroll
    for (int kk = 0; kk < 64; kk += 32) {
      bf16x8 a[2], b[2];
#pragma unroll
      for (int m = 0; m < 2; ++m)
        a[m] = *(const bf16x8*)&lsA[(wr * 32 + m * 16 + lr) * 64 + kk + lk];
#pragma unroll
      for (int n = 0; n < 2; ++n)
        b[n] = *(const bf16x8*)&lsB[(wc * 32 + n * 16 + lr) * 64 + kk + lk];
#pragma unroll
      for (int m = 0; m < 2; ++m)
#pragma unroll
        for (int n = 0; n < 2; ++n)
          acc[m][n] = __builtin_amdgcn_mfma_f32_16x16x32_bf16(a[m], b[n], acc[m][n], 0, 0, 0);
    }
    __syncthreads();
  }

#pragma unroll
  for (int m = 0; m < 2; ++m)
#pragma unroll
    for (int i2 = 0; i2 < 4; ++i2) {
      const int lrow = wr * 32 + m * 16 + ((l >> 4) << 2) + i2;
      if (t0 + lrow >= cnt) continue;
      const int gr = perm[b0 + t0 + lrow];
#pragma unroll
      for (int n = 0; n < 2; ++n) {
        const int col = c0 + wc * 32 + n * 16 + lr;
        float v = acc[m][n][i2] + bc1[d * 256 + col];
        v = fmaxf(v, 0.f);
        h[(long)gr * 256 + col] = f2b(v);
      }
    }
}

// ---------------- logits GEMV: one wave per row ----------------
__global__ __launch_bounds__(256)
void logits_k(const short* __restrict__ h, const float* __restrict__ Wc2,
              const float* __restrict__ bc2, const int* __restrict__ didx,
              float* __restrict__ out) {
  const int w = threadIdx.x >> 6, l = threadIdx.x & 63;
  const int r = (blockIdx.x << 2) + w;
  const int d = didx[r];
  const short4 hv4 = *(const short4*)(h + (long)r * 256 + (l << 2));
  const float* wr_ = Wc2 + d * 512 + (l << 3);
  const float4 w01 = *(const float4*)wr_;
  const float4 w23 = *(const float4*)(wr_ + 4);
  const float h0 = b2f(hv4.x), h1 = b2f(hv4.y), h2 = b2f(hv4.z), h3 = b2f(hv4.w);
  float a0 = h0 * w01.x + h1 * w01.z + h2 * w23.x + h3 * w23.z;
  float a1 = h0 * w01.y + h1 * w01.w + h2 * w23.y + h3 * w23.w;
#pragma unroll
  for (int off = 32; off > 0; off >>= 1) {
    a0 += __shfl_down(a0, off);
    a1 += __shfl_down(a1, off);
  }
  if (l == 0) {
    out[r * 2 + 0] = a0 + bc2[d * 2 + 0];
    out[r * 2 + 1] = a1 + bc2[d * 2 + 1];
  }
}

// ---------------- emotion layer-2 GEMV: one wave per row ----------------
__global__ __launch_bounds__(256)
void emo2_k(const short* __restrict__ e1, const float* __restrict__ We2,
            const float* __restrict__ be2, float* __restrict__ out) {
  const int w = threadIdx.x >> 6, l = threadIdx.x & 63;
  const int r = (blockIdx.x << 2) + w;
  const float h0 = b2f(e1[(long)r * 128 + 2 * l]);
  const float h1 = b2f(e1[(long)r * 128 + 2 * l + 1]);
  const float* w0 = We2 + (2 * l) * 8;
  float a[8];
#pragma unroll
  for (int c = 0; c < 8; ++c) a[c] = h0 * w0[c] + h1 * w0[8 + c];
#pragma unroll
  for (int c = 0; c < 8; ++c)
#pragma unroll
    for (int off = 32; off > 0; off >>= 1) a[c] += __shfl_down(a[c], off);
  if (l == 0) {
#pragma unroll
    for (int c = 0; c < 8; ++c) out[r * 8 + c] = a[c] + be2[c];
  }
}

// ---------------- launch ----------------
extern "C" void kernel_launch(void* const* d_in, const int* in_sizes, int n_in,
                              void* d_out, int out_size, void* d_ws, size_t ws_size,
                              hipStream_t stream) {
  const float* audio = (const float*)d_in[0];
  const float* video = (const float*)d_in[1];
  const int*   didx  = (const int*)d_in[2];
  const float* Wa    = (const float*)d_in[3];
  const float* ba    = (const float*)d_in[4];
  const float* Wv    = (const float*)d_in[5];
  const float* bv    = (const float*)d_in[6];
  const float* Pa    = (const float*)d_in[7];
  const float* Cva   = (const float*)d_in[8];
  const float* Pv    = (const float*)d_in[9];
  const float* Cav   = (const float*)d_in[10];
  const float* Wproj = (const float*)d_in[11];
  const float* bproj = (const float*)d_in[12];
  const float* Wf    = (const float*)d_in[13];
  const float* bfv   = (const float*)d_in[14];
  const float* Wc1   = (const float*)d_in[15];
  const float* bc1   = (const float*)d_in[16];
  const float* Wc2   = (const float*)d_in[17];
  const float* bc2   = (const float*)d_in[18];
  const float* We1   = (const float*)d_in[19];
  const float* be1   = (const float*)d_in[20];
  const float* We2   = (const float*)d_in[21];
  const float* be2   = (const float*)d_in[22];

  char* ws = (char*)d_ws;
  short* a_bf    = (short*)(ws + 0);          // dead after enc_gemm
  short* v_bf    = (short*)(ws + 6291456);    // dead after enc_gemm
  short* W2T     = (short*)(ws + 0);          // aliases a_bf (2MB, written after enc)
  short* WaT     = (short*)(ws + 23068672);
  short* WvT     = (short*)(ws + 23855104);
  short* Watt_rm = (short*)(ws + 25952256);   // 1024x2048 bf16 = 4MB
  short* WprojT  = (short*)(ws + 30146560);   // 2048 rows x 2048 k?? (1024x2048) 4MB
  short* WfT     = (short*)(ws + 34340864);
  short* Wc1T    = (short*)(ws + 40632320);
  short* We1T    = (short*)(ws + 49020928);
  short* afvf    = (short*)(ws + 49152000);
  short* fusedA  = (short*)(ws + 57540608);
  short* fusedB  = (short*)(ws + 65929216);
  short* h_bf    = (short*)(ws + 74317824);
  short* e1_bf   = (short*)(ws + 76414976);
  int*   perm    = (int*)(ws + 77463552);
  int*   bstart  = (int*)(ws + 77479936);     // 18 ints
  int*   bmap    = (int*)(ws + 77480064);     // 128 ints

  float* out        = (float*)d_out;
  float* out_logits = out;
  float* out_af     = out + 8192;
  float* out_vf     = out + 2105344;
  float* out_fused  = out + 4202496;
  float* out_emo    = out + 8396800;

  // f32 -> bf16 conversions
  conv_k<<<dim3(3072), dim3(256), 0, stream>>>(audio, a_bf, 3145728);
  conv_k<<<dim3(8192), dim3(256), 0, stream>>>(video, v_bf, 8388608);
  // weight transposes (out[n][k] = in[k][n])
  convT_k<<<dim3(16, 24, 1), dim3(256), 0, stream>>>(Wa, WaT, 512, 768, 0, 0);
  convT_k<<<dim3(16, 64, 1), dim3(256), 0, stream>>>(Wv, WvT, 512, 2048, 0, 0);
  convT_k<<<dim3(32, 64, 1), dim3(256), 0, stream>>>(Wproj, WprojT, 1024, 2048, 0, 0);
  convT_k<<<dim3(32, 32, 3), dim3(256), 0, stream>>>(Wf, WfT, 1024, 1024, 1048576, 1048576);
  convT_k<<<dim3(8, 32, 16), dim3(256), 0, stream>>>(Wc1, Wc1T, 256, 1024, 262144, 262144);
  convT_k<<<dim3(4, 16, 1), dim3(256), 0, stream>>>(We1, We1T, 128, 512, 0, 0);
  // Watt row-major (no transpose needed): [[Pa, Cav],[Cva, Pv]]
  conv4_k<<<dim3(512, 4), dim3(256), 0, stream>>>(Pa, Cva, Cav, Pv, Watt_rm);

  // bucketing early (independent of GEMM chain)
  bucket_k<<<dim3(1), dim3(1024), 0, stream>>>(didx, perm, bstart, bmap);

  // G1+G2 fused: af|vf = relu([audio,video] @ [Wa,Wv] + b) -> afvf + f32 outs
  enc_gemm<<<dim3(32, 16), dim3(256), 0, stream>>>(
      a_bf, v_bf, WaT, WvT, ba, bv, afvf, out_af, out_vf);

  // W2T = (Watt @ Wproj)^T : C[i][n] = sum_k WprojT[i][k] * Watt_rm[n][k]
  // (a_bf is dead now; W2T reuses its space)
  gemm_bt<64, 64, false, false><<<dim3(16, 16), dim3(256), 0, stream>>>(
      WprojT, Watt_rm, nullptr, W2T, 1024, nullptr, 0, 2048, 2048, 2048);

  // G3+G4 fused: fused0 = afvf @ W2 + bproj  (no relu)
  gemm_bt<128, 64, false, false><<<dim3(32, 16), dim3(256), 0, stream>>>(
      afvf, W2T, bproj, fusedA, 1024, nullptr, 0, 1024, 1024, 1024);
  // G5..G7: MLP (128x64 tiles -> 512 blocks = 2/CU)
  gemm_bt<128, 64, true, false><<<dim3(32, 16), dim3(256), 0, stream>>>(
      fusedA, WfT, bfv, fusedB, 1024, nullptr, 0, 1024, 1024, 1024);
  gemm_bt<128, 64, true, false><<<dim3(32, 16), dim3(256), 0, stream>>>(
      fusedB, WfT + 1048576, bfv + 1024, fusedA, 1024, nullptr, 0, 1024, 1024, 1024);
  gemm_bt<128, 64, true, true><<<dim3(32, 16), dim3(256), 0, stream>>>(
      fusedA, WfT + 2097152, bfv + 2048, fusedB, 1024, out_fused, 1024, 1024, 1024, 1024);
  // emotion layer 1: e1 = relu(vf@We1+be1)  (64x32 tiles -> 256 blocks)
  gemm_bt<64, 32, true, false><<<dim3(64, 4), dim3(256), 0, stream>>>(
      afvf + 512, We1T, be1, e1_bf, 128, nullptr, 0, 512, 1024, 512);

  // heads
  head_gemm<<<dim3(80, 4), dim3(256), 0, stream>>>(fusedB, Wc1T, bc1, perm, bstart, bmap, h_bf);
  logits_k<<<dim3(1024), dim3(256), 0, stream>>>(h_bf, Wc2, bc2, didx, out_logits);
  emo2_k<<<dim3(1024), dim3(256), 0, stream>>>(e1_bf, We2, be2, out_emo);
}

// Round 5
// 205.746 us; speedup vs baseline: 1.5480x; 1.0826x over previous
//
#include <hip/hip_runtime.h>
#include <hip/hip_bf16.h>
#include <stdint.h>

// Sizes (fixed): B=4096, A=768, V=2048, H=512, F=1024, ND=16, NC=2, NE=8, NL=3

typedef __attribute__((ext_vector_type(8))) short bf16x8;
typedef __attribute__((ext_vector_type(4))) float f32x4;

__device__ inline short f2b(float f) {
  union { float f; uint32_t u; } a; a.f = f;
  uint32_t r = a.u + 0x7fffu + ((a.u >> 16) & 1u);   // RNE
  return (short)(r >> 16);
}
__device__ inline float b2f(short s) {
  union { uint32_t u; float f; } a; a.u = ((uint32_t)(uint16_t)s) << 16;
  return a.f;
}
__device__ inline void gload_lds16(const void* g, void* l) {
  __builtin_amdgcn_global_load_lds(
      (const __attribute__((address_space(1))) uint32_t*)g,
      (__attribute__((address_space(3))) uint32_t*)l, 16, 0, 0);
}

// ---------------- single weight-prep kernel ----------------
// Segments (block ranges):
//  [0,384)      Wa   768x512   -> WaT   (512 rows x 768)
//  [384,1408)   Wv   2048x512  -> WvT
//  [1408,3456)  Wproj 2048x1024-> WprojT
//  [3456,6528)  Wf   3x1024x1024 -> WfT
//  [6528,10624) Wc1  16x1024x256 -> Wc1T
//  [10624,10688) We1 512x128   -> We1T
//  [10688,12736) Watt_rm build: [[Pa,Cav],[Cva,Pv]] row-major 1024x2048
__global__ __launch_bounds__(256)
void prep_k(const float* __restrict__ Wa, const float* __restrict__ Wv,
            const float* __restrict__ Wproj, const float* __restrict__ Wf,
            const float* __restrict__ Wc1, const float* __restrict__ We1,
            const float* __restrict__ Pa, const float* __restrict__ Cva,
            const float* __restrict__ Cav, const float* __restrict__ Pv,
            short* __restrict__ WaT, short* __restrict__ WvT,
            short* __restrict__ WprojT, short* __restrict__ WfT,
            short* __restrict__ Wc1T, short* __restrict__ We1T,
            short* __restrict__ Watt) {
  __shared__ float t[32][33];
  int b = blockIdx.x;
  const float* in; short* out; int N, ldout, bx, by;
  if (b < 384)        { in = Wa;    out = WaT;    N = 512;  ldout = 768;  bx = b & 15; by = b >> 4; }
  else if (b < 1408)  { b -= 384;  in = Wv;    out = WvT;    N = 512;  ldout = 2048; bx = b & 15; by = b >> 4; }
  else if (b < 3456)  { b -= 1408; in = Wproj; out = WprojT; N = 1024; ldout = 2048; bx = b & 31; by = b >> 5; }
  else if (b < 6528)  { b -= 3456; int z = b >> 10; b &= 1023;
                        in = Wf + (long)z * 1048576; out = WfT + (long)z * 1048576;
                        N = 1024; ldout = 1024; bx = b & 31; by = b >> 5; }
  else if (b < 10624) { b -= 6528; int z = b >> 8; b &= 255;
                        in = Wc1 + (long)z * 262144; out = Wc1T + (long)z * 262144;
                        N = 256; ldout = 1024; bx = b & 7; by = b >> 3; }
  else if (b < 10688) { b -= 10624; in = We1; out = We1T; N = 128; ldout = 512; bx = b & 3; by = b >> 2; }
  else {
    b -= 10688;
    const int h = b & 511, q = b >> 9;
    const float* src; int rowoff, coloff;
    if (q == 0)      { src = Pa;  rowoff = 0;   coloff = 0; }
    else if (q == 1) { src = Cav; rowoff = 0;   coloff = 1024; }
    else if (q == 2) { src = Cva; rowoff = 512; coloff = 0; }
    else             { src = Pv;  rowoff = 512; coloff = 1024; }
    const int j = threadIdx.x << 2;
    float4 v = *(const float4*)(src + (long)h * 1024 + j);
    short4 o; o.x = f2b(v.x); o.y = f2b(v.y); o.z = f2b(v.z); o.w = f2b(v.w);
    *(short4*)(Watt + (long)(rowoff + h) * 2048 + coloff + j) = o;
    return;
  }
  const int tx = threadIdx.x & 31, ty = threadIdx.x >> 5;  // 32 x 8
  const int n0 = bx << 5, k0 = by << 5;
#pragma unroll
  for (int i = 0; i < 4; ++i)
    t[ty + 8 * i][tx] = in[(long)(k0 + ty + 8 * i) * N + n0 + tx];
  __syncthreads();
#pragma unroll
  for (int i = 0; i < 4; ++i)
    out[(long)(n0 + ty + 8 * i) * ldout + k0 + tx] = f2b(t[tx][ty + 8 * i]);
}

// ---------------- templated GEMM body: C = A(MxK) * BT(NxK)^T ----------------
// 4 waves as 2x2; per-wave (BM/2)x(BN/2); BK=64; 16x16x32 MFMA.
// LDS staging layout (both paths): chunk i (32 rows), thread tid writes/covers
// bytes [i*4096 + tid*16, +16) == row (tid>>3)+32i, cols (tid&7)*8..+8 (bf16).
// AF32: A is f32; reg-stage two float4 + convert + one b128 LDS write.
template<int BM, int BN, bool RELU, bool HASF32, bool AF32>
__device__ __forceinline__
void gemm_body(const void* __restrict__ Av, const short* __restrict__ BT,
               const float* __restrict__ bias,
               short* __restrict__ Cb, int ldcb,
               float* __restrict__ Cf, int ldcf,
               int K, int lda, int ldbt, int m0, int n0,
               short* lsA, short* lsB) {
  constexpr int MR = BM / 32, NR = BN / 32;
  const int tid = threadIdx.x;
  const int w = tid >> 6, l = tid & 63;
  const int wr = w >> 1, wc = w & 1;
  const int lr = l & 15, lk = (l >> 4) << 3;

  f32x4 acc[MR][NR];
#pragma unroll
  for (int m = 0; m < MR; ++m)
#pragma unroll
    for (int n = 0; n < NR; ++n) acc[m][n] = (f32x4)0.f;

  const int r_ = tid >> 3;            // 0..31
  const int kc_ = (tid & 7) << 3;     // 0..56 (elements)
  const short* Arow = AF32 ? nullptr : (const short*)Av + (long)(m0 + r_) * lda + kc_;
  const float* Afrow = AF32 ? (const float*)Av + (long)(m0 + r_) * lda + kc_ : nullptr;
  const short* Brow = BT + (long)(n0 + r_) * ldbt + kc_;

  for (int kt = 0; kt < K; kt += 64) {
#pragma unroll
    for (int i = 0; i < BN / 32; ++i)
      gload_lds16(Brow + (long)i * 32 * ldbt + kt, (char*)lsB + i * 4096 + w * 1024);
    if constexpr (AF32) {
#pragma unroll
      for (int i = 0; i < BM / 32; ++i) {
        const float* p = Afrow + (long)i * 32 * lda + kt;
        const float4 v0 = *(const float4*)p;
        const float4 v1 = *(const float4*)(p + 4);
        bf16x8 o;
        o[0] = f2b(v0.x); o[1] = f2b(v0.y); o[2] = f2b(v0.z); o[3] = f2b(v0.w);
        o[4] = f2b(v1.x); o[5] = f2b(v1.y); o[6] = f2b(v1.z); o[7] = f2b(v1.w);
        *(bf16x8*)((char*)lsA + i * 4096 + tid * 16) = o;
      }
    } else {
#pragma unroll
      for (int i = 0; i < BM / 32; ++i)
        gload_lds16(Arow + (long)i * 32 * lda + kt, (char*)lsA + i * 4096 + w * 1024);
    }
    __syncthreads();
#pragma unroll
    for (int kk = 0; kk < 64; kk += 32) {
      bf16x8 a[MR], b[NR];
#pragma unroll
      for (int m = 0; m < MR; ++m)
        a[m] = *(const bf16x8*)&lsA[(wr * (BM / 2) + m * 16 + lr) * 64 + kk + lk];
#pragma unroll
      for (int n = 0; n < NR; ++n)
        b[n] = *(const bf16x8*)&lsB[(wc * (BN / 2) + n * 16 + lr) * 64 + kk + lk];
#pragma unroll
      for (int m = 0; m < MR; ++m)
#pragma unroll
        for (int n = 0; n < NR; ++n)
          acc[m][n] = __builtin_amdgcn_mfma_f32_16x16x32_bf16(a[m], b[n], acc[m][n], 0, 0, 0);
    }
    __syncthreads();
  }

  const int lrow = (l >> 4) << 2;
#pragma unroll
  for (int n = 0; n < NR; ++n) {
    const int col = n0 + wc * (BN / 2) + n * 16 + lr;
    const float bz = bias ? bias[col] : 0.f;
#pragma unroll
    for (int m = 0; m < MR; ++m) {
      const int rowb = m0 + wr * (BM / 2) + m * 16 + lrow;
#pragma unroll
      for (int i = 0; i < 4; ++i) {
        float v = acc[m][n][i] + bz;
        if (RELU) v = fmaxf(v, 0.f);
        Cb[(long)(rowb + i) * ldcb + col] = f2b(v);
        if (HASF32) Cf[(long)(rowb + i) * ldcf + col] = v;
      }
    }
  }
}

template<int BM, int BN, bool RELU, bool HASF32>
__global__ __launch_bounds__(256, 2)
void gemm_bt(const short* __restrict__ A, const short* __restrict__ BT,
             const float* __restrict__ bias,
             short* __restrict__ Cb, int ldcb,
             float* __restrict__ Cf, int ldcf,
             int K, int lda, int ldbt) {
  __shared__ short lsA[BM * 64];
  __shared__ short lsB[BN * 64];
  gemm_body<BM, BN, RELU, HASF32, false>(A, BT, bias, Cb, ldcb, Cf, ldcf,
                                         K, lda, ldbt, blockIdx.x * BM, blockIdx.y * BN,
                                         lsA, lsB);
}

// Fused audio+video encoder, reading f32 inputs directly.
// blockIdx.y<8 -> audio GEMM, else video GEMM.
__global__ __launch_bounds__(256, 2)
void enc_gemm(const float* __restrict__ audio, const float* __restrict__ video,
              const short* __restrict__ WaT, const short* __restrict__ WvT,
              const float* __restrict__ ba, const float* __restrict__ bv,
              short* __restrict__ afvf, float* __restrict__ out_af,
              float* __restrict__ out_vf) {
  __shared__ short lsA[128 * 64];
  __shared__ short lsB[64 * 64];
  const bool isA = blockIdx.y < 8;
  gemm_body<128, 64, true, true, true>(
      isA ? audio : video, isA ? WaT : WvT, isA ? ba : bv,
      afvf + (isA ? 0 : 512), 1024, isA ? out_af : out_vf, 512,
      isA ? 768 : 2048, isA ? 768 : 2048, isA ? 768 : 2048,
      blockIdx.x * 128, (blockIdx.y & 7) * 64, lsA, lsB);
}

// ---------------- disease bucketing + block map ----------------
__global__ __launch_bounds__(1024)
void bucket_k(const int* __restrict__ didx, int* __restrict__ perm,
              int* __restrict__ bstart, int* __restrict__ bmap) {
  __shared__ int cnt[16], base[17], cur[16];
  const int tid = threadIdx.x;
  if (tid < 16) cnt[tid] = 0;
  __syncthreads();
  for (int r = tid; r < 4096; r += 1024) atomicAdd(&cnt[didx[r]], 1);
  __syncthreads();
  if (tid == 0) {
    int s = 0;
    for (int d = 0; d < 16; ++d) { base[d] = s; s += cnt[d]; }
    base[16] = s;
    int nb = 0;
    for (int d = 0; d < 16; ++d) {
      int nblk = (cnt[d] + 63) >> 6;
      for (int i = 0; i < nblk; ++i) bmap[nb++] = (d << 8) | i;
    }
    bstart[17] = nb;
  }
  __syncthreads();
  if (tid < 16) cur[tid] = base[tid];
  if (tid < 17) bstart[tid] = base[tid];
  __syncthreads();
  for (int r = tid; r < 4096; r += 1024) {
    int p = atomicAdd(&cur[didx[r]], 1);
    perm[p] = r;
  }
}

// ---------------- per-disease head GEMM (gathered rows) ----------------
// 64x64 tiles; grid (80, 4): x = flat (disease,rowtile) via bmap, y = col tile.
__global__ __launch_bounds__(256, 2)
void head_gemm(const short* __restrict__ fused, const short* __restrict__ Wc1T,
               const float* __restrict__ bc1, const int* __restrict__ perm,
               const int* __restrict__ bstart, const int* __restrict__ bmap,
               short* __restrict__ h) {
  const int nb = bstart[17];
  if ((int)blockIdx.x >= nb) return;
  const int me = bmap[blockIdx.x];
  const int d = me >> 8, rt = me & 0xff;
  const int b0 = bstart[d], cnt = bstart[d + 1] - b0;
  const int t0 = rt << 6;
  const int c0 = blockIdx.y << 6;
  __shared__ short lsA[64 * 64];
  __shared__ short lsB[64 * 64];
  const int tid = threadIdx.x, w = tid >> 6, l = tid & 63;
  const int wr = w >> 1, wc = w & 1;
  const int lr = l & 15, lk = (l >> 4) << 3;
  const short* BT = Wc1T + (long)d * (256 * 1024) + (long)c0 * 1024;

  f32x4 acc[2][2];
#pragma unroll
  for (int m = 0; m < 2; ++m)
#pragma unroll
    for (int n = 0; n < 2; ++n) acc[m][n] = (f32x4)0.f;

  const int r_ = tid >> 3, kc_ = (tid & 7) << 3;
  int gr0 = (t0 + r_      < cnt) ? perm[b0 + t0 + r_]      : perm[b0];
  int gr1 = (t0 + r_ + 32 < cnt) ? perm[b0 + t0 + r_ + 32] : perm[b0];
  const short* A0 = fused + (long)gr0 * 1024 + kc_;
  const short* A1 = fused + (long)gr1 * 1024 + kc_;
  const short* Brow = BT + (long)r_ * 1024 + kc_;

  for (int kt = 0; kt < 1024; kt += 64) {
    gload_lds16(A0 + kt, (char*)lsA + w * 1024);
    gload_lds16(A1 + kt, (char*)lsA + 4096 + w * 1024);
    gload_lds16(Brow + kt, (char*)lsB + w * 1024);
    gload_lds16(Brow + 32 * 1024 + kt, (char*)lsB + 4096 + w * 1024);
    __syncthreads();
#pragma unroll
    for (int kk = 0; kk < 64; kk += 32) {
      bf16x8 a[2], b[2];
#pragma unroll
      for (int m = 0; m < 2; ++m)
        a[m] = *(const bf16x8*)&lsA[(wr * 32 + m * 16 + lr) * 64 + kk + lk];
#pragma unroll
      for (int n = 0; n < 2; ++n)
        b[n] = *(const bf16x8*)&lsB[(wc * 32 + n * 16 + lr) * 64 + kk + lk];
#pragma unroll
      for (int m = 0; m < 2; ++m)
#pragma unroll
        for (int n = 0; n < 2; ++n)
          acc[m][n] = __builtin_amdgcn_mfma_f32_16x16x32_bf16(a[m], b[n], acc[m][n], 0, 0, 0);
    }
    __syncthreads();
  }

#pragma unroll
  for (int m = 0; m < 2; ++m)
#pragma unroll
    for (int i2 = 0; i2 < 4; ++i2) {
      const int lrow = wr * 32 + m * 16 + ((l >> 4) << 2) + i2;
      if (t0 + lrow >= cnt) continue;
      const int gr = perm[b0 + t0 + lrow];
#pragma unroll
      for (int n = 0; n < 2; ++n) {
        const int col = c0 + wc * 32 + n * 16 + lr;
        float v = acc[m][n][i2] + bc1[d * 256 + col];
        v = fmaxf(v, 0.f);
        h[(long)gr * 256 + col] = f2b(v);
      }
    }
}

// ---------------- logits GEMV: one wave per row ----------------
__global__ __launch_bounds__(256)
void logits_k(const short* __restrict__ h, const float* __restrict__ Wc2,
              const float* __restrict__ bc2, const int* __restrict__ didx,
              float* __restrict__ out) {
  const int w = threadIdx.x >> 6, l = threadIdx.x & 63;
  const int r = (blockIdx.x << 2) + w;
  const int d = didx[r];
  const short4 hv4 = *(const short4*)(h + (long)r * 256 + (l << 2));
  const float* wr_ = Wc2 + d * 512 + (l << 3);
  const float4 w01 = *(const float4*)wr_;
  const float4 w23 = *(const float4*)(wr_ + 4);
  const float h0 = b2f(hv4.x), h1 = b2f(hv4.y), h2 = b2f(hv4.z), h3 = b2f(hv4.w);
  float a0 = h0 * w01.x + h1 * w01.z + h2 * w23.x + h3 * w23.z;
  float a1 = h0 * w01.y + h1 * w01.w + h2 * w23.y + h3 * w23.w;
#pragma unroll
  for (int off = 32; off > 0; off >>= 1) {
    a0 += __shfl_down(a0, off);
    a1 += __shfl_down(a1, off);
  }
  if (l == 0) {
    out[r * 2 + 0] = a0 + bc2[d * 2 + 0];
    out[r * 2 + 1] = a1 + bc2[d * 2 + 1];
  }
}

// ---------------- emotion layer-2 GEMV: one wave per row ----------------
__global__ __launch_bounds__(256)
void emo2_k(const short* __restrict__ e1, const float* __restrict__ We2,
            const float* __restrict__ be2, float* __restrict__ out) {
  const int w = threadIdx.x >> 6, l = threadIdx.x & 63;
  const int r = (blockIdx.x << 2) + w;
  const float h0 = b2f(e1[(long)r * 128 + 2 * l]);
  const float h1 = b2f(e1[(long)r * 128 + 2 * l + 1]);
  const float* w0 = We2 + (2 * l) * 8;
  float a[8];
#pragma unroll
  for (int c = 0; c < 8; ++c) a[c] = h0 * w0[c] + h1 * w0[8 + c];
#pragma unroll
  for (int c = 0; c < 8; ++c)
#pragma unroll
    for (int off = 32; off > 0; off >>= 1) a[c] += __shfl_down(a[c], off);
  if (l == 0) {
#pragma unroll
    for (int c = 0; c < 8; ++c) out[r * 8 + c] = a[c] + be2[c];
  }
}

// ---------------- launch ----------------
extern "C" void kernel_launch(void* const* d_in, const int* in_sizes, int n_in,
                              void* d_out, int out_size, void* d_ws, size_t ws_size,
                              hipStream_t stream) {
  const float* audio = (const float*)d_in[0];
  const float* video = (const float*)d_in[1];
  const int*   didx  = (const int*)d_in[2];
  const float* Wa    = (const float*)d_in[3];
  const float* ba    = (const float*)d_in[4];
  const float* Wv    = (const float*)d_in[5];
  const float* bv    = (const float*)d_in[6];
  const float* Pa    = (const float*)d_in[7];
  const float* Cva   = (const float*)d_in[8];
  const float* Pv    = (const float*)d_in[9];
  const float* Cav   = (const float*)d_in[10];
  const float* Wproj = (const float*)d_in[11];
  const float* bproj = (const float*)d_in[12];
  const float* Wf    = (const float*)d_in[13];
  const float* bfv   = (const float*)d_in[14];
  const float* Wc1   = (const float*)d_in[15];
  const float* bc1   = (const float*)d_in[16];
  const float* Wc2   = (const float*)d_in[17];
  const float* bc2   = (const float*)d_in[18];
  const float* We1   = (const float*)d_in[19];
  const float* be1   = (const float*)d_in[20];
  const float* We2   = (const float*)d_in[21];
  const float* be2   = (const float*)d_in[22];

  char* ws = (char*)d_ws;
  short* W2T     = (short*)(ws + 0);          // 1024x1024 bf16 = 2MB
  short* WaT     = (short*)(ws + 2097152);    // 512x768
  short* WvT     = (short*)(ws + 2883584);    // 512x2048
  short* Watt_rm = (short*)(ws + 4980736);    // 1024x2048 = 4MB
  short* WprojT  = (short*)(ws + 9175040);    // 1024x2048 = 4MB
  short* WfT     = (short*)(ws + 13369344);   // 3x1024x1024 = 6MB
  short* Wc1T    = (short*)(ws + 19660800);   // 16x256x1024 = 8MB
  short* We1T    = (short*)(ws + 28049408);   // 128x512
  short* afvf    = (short*)(ws + 28180480);   // 4096x1024 = 8MB
  short* fusedA  = (short*)(ws + 36569088);   // 8MB
  short* fusedB  = (short*)(ws + 44957696);   // 8MB
  short* h_bf    = (short*)(ws + 53346304);   // 4096x256 = 2MB
  short* e1_bf   = (short*)(ws + 55443456);   // 4096x128 = 1MB
  int*   perm    = (int*)(ws + 56492032);     // 4096 ints
  int*   bstart  = (int*)(ws + 56508416);     // 18 ints
  int*   bmap    = (int*)(ws + 56508544);     // 128 ints

  float* out        = (float*)d_out;
  float* out_logits = out;
  float* out_af     = out + 8192;
  float* out_vf     = out + 2105344;
  float* out_fused  = out + 4202496;
  float* out_emo    = out + 8396800;

  // all weight conversions in one dispatch
  prep_k<<<dim3(12736), dim3(256), 0, stream>>>(
      Wa, Wv, Wproj, Wf, Wc1, We1, Pa, Cva, Cav, Pv,
      WaT, WvT, WprojT, WfT, Wc1T, We1T, Watt_rm);

  // bucketing (independent of GEMM chain)
  bucket_k<<<dim3(1), dim3(1024), 0, stream>>>(didx, perm, bstart, bmap);

  // G1+G2 fused, f32 inputs consumed directly
  enc_gemm<<<dim3(32, 16), dim3(256), 0, stream>>>(
      audio, video, WaT, WvT, ba, bv, afvf, out_af, out_vf);

  // W2T = (Watt @ Wproj)^T : C[i][n] = sum_k WprojT[i][k] * Watt_rm[n][k]
  gemm_bt<64, 32, false, false><<<dim3(16, 32), dim3(256), 0, stream>>>(
      WprojT, Watt_rm, nullptr, W2T, 1024, nullptr, 0, 2048, 2048, 2048);

  // G3+G4 fused: fused0 = afvf @ W2 + bproj  (no relu)
  gemm_bt<128, 64, false, false><<<dim3(32, 16), dim3(256), 0, stream>>>(
      afvf, W2T, bproj, fusedA, 1024, nullptr, 0, 1024, 1024, 1024);
  // G5..G7: MLP (128x64 tiles -> 512 blocks = 2/CU)
  gemm_bt<128, 64, true, false><<<dim3(32, 16), dim3(256), 0, stream>>>(
      fusedA, WfT, bfv, fusedB, 1024, nullptr, 0, 1024, 1024, 1024);
  gemm_bt<128, 64, true, false><<<dim3(32, 16), dim3(256), 0, stream>>>(
      fusedB, WfT + 1048576, bfv + 1024, fusedA, 1024, nullptr, 0, 1024, 1024, 1024);
  gemm_bt<128, 64, true, true><<<dim3(32, 16), dim3(256), 0, stream>>>(
      fusedA, WfT + 2097152, bfv + 2048, fusedB, 1024, out_fused, 1024, 1024, 1024, 1024);
  // emotion layer 1: e1 = relu(vf@We1+be1)
  gemm_bt<64, 32, true, false><<<dim3(64, 4), dim3(256), 0, stream>>>(
      afvf + 512, We1T, be1, e1_bf, 128, nullptr, 0, 512, 1024, 512);

  // heads
  head_gemm<<<dim3(80, 4), dim3(256), 0, stream>>>(fusedB, Wc1T, bc1, perm, bstart, bmap, h_bf);
  logits_k<<<dim3(1024), dim3(256), 0, stream>>>(h_bf, Wc2, bc2, didx, out_logits);
  emo2_k<<<dim3(1024), dim3(256), 0, stream>>>(e1_bf, We2, be2, out_emo);
}